// Round 8
// baseline (129.242 us; speedup 1.0000x reference)
//
#include <hip/hip_runtime.h>
#include <math.h>

// Problem constants (B,C,H,W = 8,256,64,64; N = H*W = 4096)
#define BQ 8
#define CQ 256
#define NQ 4096
#define MT 64             // m-tile per block (512 blocks -> 2 per CU)
#define NSUP 64           // supersteps (2 chunks of 32n each)

typedef short s16x8 __attribute__((ext_vector_type(8)));
typedef short s16x4 __attribute__((ext_vector_type(4)));
typedef float f32x4 __attribute__((ext_vector_type(4)));
typedef unsigned int uint;

static __device__ __forceinline__ float4 ld4(const float* p) { return *(const float4*)p; }

static constexpr float LOG2E = 1.4426950408889634f;

static __device__ __forceinline__ short f2bf(float f) {
    return __builtin_bit_cast(short, (__bf16)f);
}
// monotonic uint key for float compare via atomicMax/Min
static __device__ __forceinline__ uint fkey(float f) {
    uint b = __builtin_bit_cast(uint, f);
    return b ^ (0x80000000u | (uint)((int)b >> 31));
}
static __device__ __forceinline__ float fdec(uint u) {
    uint b = (u & 0x80000000u) ? (u ^ 0x80000000u) : ~u;
    return __builtin_bit_cast(float, b);
}

// -------- K1: f' = (wq.x)*log2e, g = wk.x, xbf = bf16(x), fused batch max/min --------
__global__ void k_fg(const float* __restrict__ x, const float* __restrict__ wq,
                     const float* __restrict__ wk, float* __restrict__ fs,
                     float* __restrict__ g, short* __restrict__ xbf,
                     uint* __restrict__ fmxu, uint* __restrict__ fmnu) {
    int b = blockIdx.y;
    int t = threadIdx.x;
    int nl = (t & 31) * 2;
    int cg = t >> 5;                     // 0..7
    int n = blockIdx.x * 64 + nl;
    const float* xb = x + (size_t)b * CQ * NQ + n;
    uint* xo = (uint*)(xbf + (size_t)b * CQ * NQ + n);
    float f0 = 0.f, f1 = 0.f, g0 = 0.f, g1 = 0.f;
    int c0 = cg * 32;
#pragma unroll 8
    for (int c = c0; c < c0 + 32; ++c) {
        float2 v = *(const float2*)&xb[(size_t)c * NQ];
        f0 = fmaf(wq[c], v.x, f0);
        f1 = fmaf(wq[c], v.y, f1);
        g0 = fmaf(wk[c], v.x, g0);
        g1 = fmaf(wk[c], v.y, g1);
        uint p = (uint)(unsigned short)f2bf(v.x) | ((uint)(unsigned short)f2bf(v.y) << 16);
        xo[c * (NQ / 2)] = p;
    }
    __shared__ float sf[8][64], sg2[8][64];
    sf[cg][nl] = f0;  sf[cg][nl + 1] = f1;
    sg2[cg][nl] = g0; sg2[cg][nl + 1] = g1;
    __syncthreads();
    if (t < 64) {
        float f = 0.f, gg = 0.f;
#pragma unroll
        for (int i = 0; i < 8; ++i) { f += sf[i][t]; gg += sg2[i][t]; }
        f *= LOG2E;
        fs[b * NQ + blockIdx.x * 64 + t] = f;
        g[b * NQ + blockIdx.x * 64 + t]  = gg;
        float mx = f, mn = f;
#pragma unroll
        for (int off = 32; off; off >>= 1) {
            mx = fmaxf(mx, __shfl_xor(mx, off));
            mn = fminf(mn, __shfl_xor(mn, off));
        }
        if (t == 0) {
            atomicMax(&fmxu[b], fkey(mx));
            atomicMin(&fmnu[b], fkey(mn));
        }
    }
}

// LDS map (bytes):
//   [0, 64K)  : two 32KB pair-buffers (each 2 chunks of 256c x 32n bf16, q-swizzled);
//               post-loop overlays: merge (4 pairs x 16KB f32), then y_lds 32KB
//   [64K, 65K): zbuf (8 waves x 32 f32)
#define ZBUF_OFF 65536
#define SMEM_BYTES 66560   // 65KB -> 2 blocks/CU (133KB of 160KB)

// -------- K2 fused: y[c][m] = sum_n x[c][n] e[n,m];  o = (1-g)*wv*(y/Z) + g*x --------
// 512 blocks (2 per CU, independent barrier domains -> phase-skewed pipes),
// 512 thr, 8 waves: ws = w&1 (chunk parity), wm = (w>>1)&1 (m-half), wc = w>>2
// (c-half). Block tile 256c x 64m; wave tile 128c x 32m (jc=8 x jm=2).
// f read from global (L1-resident). Z accumulated via MFMA with A = ones.
__global__ void __launch_bounds__(512, 4) k_attn(
    const short* __restrict__ xbf, const float* __restrict__ fsp,
    const float* __restrict__ gp, const uint* __restrict__ fmxu,
    const uint* __restrict__ fmnu, const float* __restrict__ wv,
    const float* __restrict__ x, const float* __restrict__ gamma,
    float* __restrict__ out) {
    __shared__ __align__(16) char smem[SMEM_BYTES];

    int bid = blockIdx.x;
    int b = bid & 7;            // batch -> XCD affinity (2MB xbf slice per XCD L2)
    int mblk = bid >> 3;        // 0..63
    int m0 = mblk * MT;
    int tid = threadIdx.x;
    int l = tid & 63;
    int w = tid >> 6;           // 0..7
    int ws = w & 1;             // chunk within pair
    int wm = (w >> 1) & 1;      // m-half
    int wc = w >> 2;            // c-half
    int q = l >> 4;             // k-slot
    int cr = l & 15;            // A-row / B-col within frag
    int qp16 = (q ^ ((cr >> 1) & 3)) * 16;   // swizzled 16B slot for A-reads

    const short* xb = xbf + (size_t)b * CQ * NQ;
    const float* fb = fsp + b * NQ;

    // hoisted staging addresses: 4 x 8KB issues cover one 32KB pair
    // off = tid*16 + r2*8192; half = r2>>1; row = (tid>>2) + (r2&1)*128
    const short* srcs[4];
    int dsts[4];
#pragma unroll
    for (int r2 = 0; r2 < 4; ++r2) {
        int row = (tid >> 2) + (r2 & 1) * 128;
        int half = r2 >> 1;
        int lq = (tid & 3) ^ ((row >> 1) & 3);   // q-swizzle pre-applied on global src
        srcs[r2] = xb + (size_t)row * NQ + half * 32 + lq * 8;
        dsts[r2] = tid * 16 + r2 * 8192;
    }

    // ---- prolog: stage pair 0 ----
#pragma unroll
    for (int r2 = 0; r2 < 4; ++r2) {
        __builtin_amdgcn_global_load_lds(
            (const __attribute__((address_space(1))) void*)srcs[r2],
            (__attribute__((address_space(3))) void*)(smem + dsts[r2]), 16, 0, 0);
        srcs[r2] += 64;
    }

    float fmx = fdec(fmxu[b]), fmn = fdec(fmnu[b]);
    const float* gb = gp + b * NQ;
    float gj[2], nM[2];
#pragma unroll
    for (int jm = 0; jm < 2; ++jm) {
        float gv = gb[m0 + wm * 32 + jm * 16 + cr];
        gj[jm] = gv;
        nM[jm] = -((gv >= 0.f) ? gv * fmx : gv * fmn);
    }

    // ones A-frag for Z-accumulation MFMA (bf16 1.0 = 0x3F80)
    s16x8 ones;
#pragma unroll
    for (int i = 0; i < 8; ++i) ones[i] = (short)0x3F80;

    f32x4 acc[8][2];
#pragma unroll
    for (int jc = 0; jc < 8; ++jc)
#pragma unroll
        for (int jm = 0; jm < 2; ++jm) acc[jc][jm] = (f32x4){0.f, 0.f, 0.f, 0.f};
    f32x4 accz[2] = {(f32x4){0.f, 0.f, 0.f, 0.f}, (f32x4){0.f, 0.f, 0.f, 0.f}};

    __syncthreads();   // pair0 ready

    for (int s = 0; s < NSUP; ++s) {
        if (s < NSUP - 1) {   // stage pair s+1 into buffer (s+1)&1
            char* nbuf = smem + ((s + 1) & 1) * 32768;
#pragma unroll
            for (int r2 = 0; r2 < 4; ++r2) {
                __builtin_amdgcn_global_load_lds(
                    (const __attribute__((address_space(1))) void*)srcs[r2],
                    (__attribute__((address_space(3))) void*)(nbuf + dsts[r2]), 16, 0, 0);
                srcs[r2] += 64;
            }
        }
        int chunk = 2 * s + ws;
        const char* cbuf = smem + (s & 1) * 32768 + ws * 16384;
        const float* fls = fb + chunk * 32;      // L1-hot global read
        float4 fqa = ld4(fls + q * 8);
        float4 fqb = ld4(fls + q * 8 + 4);
        float fq[8] = {fqa.x, fqa.y, fqa.z, fqa.w, fqb.x, fqb.y, fqb.z, fqb.w};
        s16x8 bv[2];
#pragma unroll
        for (int jm = 0; jm < 2; ++jm) {
#pragma unroll
            for (int i = 0; i < 8; ++i)
                bv[jm][i] = f2bf(__builtin_amdgcn_exp2f(fmaf(fq[i], gj[jm], nM[jm])));
        }
        // Z via matrix pipe: accz[jm] += ones . bv[jm] (every reg = chunk-sum per col)
        accz[0] = __builtin_amdgcn_mfma_f32_16x16x32_bf16(ones, bv[0], accz[0], 0, 0, 0);
        accz[1] = __builtin_amdgcn_mfma_f32_16x16x32_bf16(ones, bv[1], accz[1], 0, 0, 0);
#pragma unroll
        for (int jc = 0; jc < 8; ++jc) {
            s16x8 av = *(const s16x8*)(cbuf + (wc * 128 + jc * 16 + cr) * 64 + qp16);
            acc[jc][0] = __builtin_amdgcn_mfma_f32_16x16x32_bf16(av, bv[0], acc[jc][0], 0, 0, 0);
            acc[jc][1] = __builtin_amdgcn_mfma_f32_16x16x32_bf16(av, bv[1], acc[jc][1], 0, 0, 0);
        }
        __syncthreads();   // pair s+1 landed; everyone done with buf (s&1)
    }

    // ---- Z: exchange across ws-partner (accz already summed over all k by MFMA) ----
    float zf[2] = {accz[0][0], accz[1][0]};
    float* zb = (float*)(smem + ZBUF_OFF);
    if (q == 0) {
#pragma unroll
        for (int jm = 0; jm < 2; ++jm) zb[w * 32 + jm * 16 + cr] = zf[jm];
    }
    __syncthreads();
#pragma unroll
    for (int jm = 0; jm < 2; ++jm) zf[jm] += zb[(w ^ 1) * 32 + jm * 16 + cr];

    // ---- acc merge across ws pairs: ws1 -> LDS (f32, 4 x 16KB), ws0 adds ----
    {
        int p = wc * 2 + wm;
        float* mrg = (float*)(smem + p * 16384);
        if (ws == 1) {
#pragma unroll
            for (int jc = 0; jc < 8; ++jc)
#pragma unroll
                for (int jm = 0; jm < 2; ++jm)
                    *(f32x4*)(mrg + ((jc * 2 + jm) * 64 + l) * 4) = acc[jc][jm];
        }
        __syncthreads();
        if (ws == 0) {
#pragma unroll
            for (int jc = 0; jc < 8; ++jc)
#pragma unroll
                for (int jm = 0; jm < 2; ++jm) {
                    f32x4 o = *(const f32x4*)(mrg + ((jc * 2 + jm) * 64 + l) * 4);
                    acc[jc][jm] += o;
                }
        }
        __syncthreads();   // merge reads done before y_lds overwrites region
    }

    // ---- y_norm -> LDS (ws0 waves): y_lds[m][c] bf16, 512B rows, XOR-swizzled ----
    if (ws == 0) {
        float rzl[2];
#pragma unroll
        for (int jm = 0; jm < 2; ++jm) rzl[jm] = 1.0f / zf[jm];
#pragma unroll
        for (int jc = 0; jc < 8; ++jc) {
#pragma unroll
            for (int jm = 0; jm < 2; ++jm) {
                int mloc = wm * 32 + jm * 16 + cr;
                int cb = (wc * 256 + jc * 32 + q * 8) ^ ((mloc & 7) << 4);
                s16x4 v;
#pragma unroll
                for (int r = 0; r < 4; ++r) v[r] = f2bf(acc[jc][jm][r] * rzl[jm]);
                *(s16x4*)(smem + mloc * 512 + cb) = v;
            }
        }
    }
    __syncthreads();

    // ---- GEMM2: o[c_out][m] = wv[c_out][:] . y_norm[:][m], K=256 (8 waves) ----
    int co0 = w * 32;
    f32x4 acc2[2][4];
#pragma unroll
    for (int j2 = 0; j2 < 2; ++j2)
#pragma unroll
        for (int jm2 = 0; jm2 < 4; ++jm2) acc2[j2][jm2] = (f32x4){0.f, 0.f, 0.f, 0.f};

#pragma unroll 2
    for (int ks = 0; ks < 8; ++ks) {
        s16x8 a2[2];
#pragma unroll
        for (int j2 = 0; j2 < 2; ++j2) {
            const float* wr = wv + (size_t)(co0 + j2 * 16 + cr) * CQ + ks * 32 + q * 8;
            float4 wa = ld4(wr);
            float4 wb = ld4(wr + 4);
            a2[j2][0] = f2bf(wa.x); a2[j2][1] = f2bf(wa.y);
            a2[j2][2] = f2bf(wa.z); a2[j2][3] = f2bf(wa.w);
            a2[j2][4] = f2bf(wb.x); a2[j2][5] = f2bf(wb.y);
            a2[j2][6] = f2bf(wb.z); a2[j2][7] = f2bf(wb.w);
        }
#pragma unroll
        for (int jm2 = 0; jm2 < 4; ++jm2) {
            int mloc = jm2 * 16 + cr;
            s16x8 b2 = *(const s16x8*)(smem + mloc * 512 + ((ks * 64 + q * 16) ^ ((mloc & 7) << 4)));
#pragma unroll
            for (int j2 = 0; j2 < 2; ++j2)
                acc2[j2][jm2] = __builtin_amdgcn_mfma_f32_16x16x32_bf16(a2[j2], b2, acc2[j2][jm2], 0, 0, 0);
        }
    }

    // ---- epilogue ----
    float gam = gamma[0];
    float omg = 1.f - gam;
    if (gam != 0.f) {
#pragma unroll
        for (int j2 = 0; j2 < 2; ++j2)
#pragma unroll
            for (int jm2 = 0; jm2 < 4; ++jm2)
#pragma unroll
                for (int r = 0; r < 4; ++r) {
                    int c_out = co0 + j2 * 16 + q * 4 + r;
                    size_t idx = ((size_t)b * CQ + c_out) * NQ + m0 + jm2 * 16 + cr;
                    __builtin_nontemporal_store(
                        fmaf(gam, x[idx], acc2[j2][jm2][r] * omg), out + idx);
                }
    } else {
#pragma unroll
        for (int j2 = 0; j2 < 2; ++j2)
#pragma unroll
            for (int jm2 = 0; jm2 < 4; ++jm2)
#pragma unroll
                for (int r = 0; r < 4; ++r) {
                    int c_out = co0 + j2 * 16 + q * 4 + r;
                    size_t idx = ((size_t)b * CQ + c_out) * NQ + m0 + jm2 * 16 + cr;
                    __builtin_nontemporal_store(acc2[j2][jm2][r] * omg, out + idx);
                }
    }
}

extern "C" void kernel_launch(void* const* d_in, const int* in_sizes, int n_in,
                              void* d_out, int out_size, void* d_ws, size_t ws_size,
                              hipStream_t stream) {
    const float* x     = (const float*)d_in[0];
    const float* wq    = (const float*)d_in[1];
    const float* wk    = (const float*)d_in[2];
    const float* wv    = (const float*)d_in[3];
    const float* gamma = (const float*)d_in[4];
    float* out = (float*)d_out;

    // ws (floats): fs[B*N] | g[B*N] | fmxu[8]+fmnu[8] (uint) | pad -> xbf (bf16) [B*C*N]
    float* ws  = (float*)d_ws;
    float* fs  = ws;
    float* g   = ws + BQ * NQ;
    uint* fmxu = (uint*)(ws + 2 * BQ * NQ);
    uint* fmnu = fmxu + 8;
    short* xbf = (short*)(ws + 2 * BQ * NQ + 64);

    hipMemsetAsync(fmxu, 0x00, 32, stream);   // lowest key
    hipMemsetAsync(fmnu, 0xFF, 32, stream);   // highest key
    hipLaunchKernelGGL(k_fg, dim3(NQ / 64, BQ), dim3(256), 0, stream,
                       x, wq, wk, fs, g, xbf, fmxu, fmnu);
    hipLaunchKernelGGL(k_attn, dim3(BQ * (NQ / MT)), dim3(512), 0, stream,
                       xbf, fs, g, fmxu, fmnu, wv, x, gamma, out);
}